// Round 10
// baseline (407.125 us; speedup 1.0000x reference)
//
#include <hip/hip_runtime.h>
#include <stdint.h>

#define B_ROWS 8192
#define P_ROWS 4096
#define D_DIM  1024
#define K_TOP  6

typedef __attribute__((ext_vector_type(8))) short short8;
typedef __attribute__((ext_vector_type(4))) float floatx4;

static __device__ __forceinline__ float bf2f(unsigned short h) {
  return __uint_as_float(((unsigned)h) << 16);
}
static __device__ __forceinline__ unsigned short f2bf(float f) {
  unsigned u = __float_as_uint(f);
  u += 0x7FFFu + ((u >> 16) & 1u);   // RNE
  return (unsigned short)(u >> 16);
}

// ---------------- bf16 MFMA GEMM body, C[m,n] = sum_d A[m,d]*W[n,d] (+ bias[n]) ----------------
typedef __attribute__((address_space(3))) unsigned int lds32_t;
typedef const __attribute__((address_space(1))) unsigned int g32_t;

static __device__ __forceinline__ void gld_lds16(const unsigned short* g, unsigned short* l) {
  __builtin_amdgcn_global_load_lds((g32_t*)(uintptr_t)g,
                                   (lds32_t*)(unsigned int)(uintptr_t)l, 16, 0, 0);
}

template <bool OUT_BF16, bool HAS_BIAS>
static __device__ __forceinline__ void gemm_bt_body(
    const unsigned short* __restrict__ A, const unsigned short* __restrict__ Bw,
    const float* __restrict__ bias, void* __restrict__ Cout, int m0, int n0) {
  constexpr int Kd = 1024, Nd = 1024, BK = 64;
  __shared__ unsigned short sA[128 * BK];
  __shared__ unsigned short sB[128 * BK];

  const int tid = threadIdx.x;
  const int wid = tid >> 6, lane = tid & 63;
  const int wm = (wid & 1) * 64, wn = (wid >> 1) * 64;

  floatx4 acc[4][4];
#pragma unroll
  for (int mt = 0; mt < 4; ++mt)
#pragma unroll
    for (int nt = 0; nt < 4; ++nt) acc[mt][nt] = (floatx4){0.f, 0.f, 0.f, 0.f};

  const int ld_row = lane >> 3;
  const int ld_col = (lane & 7) * 8;

  for (int kt = 0; kt < Kd / BK; ++kt) {
    const int k0 = kt * BK;
    __syncthreads();
#pragma unroll
    for (int c = 0; c < 4; ++c) {
      const int ch = wid * 4 + c;
      const int r = ch * 8 + ld_row;
      gld_lds16(A  + (size_t)(m0 + r) * Kd + k0 + ld_col, sA + ch * 512);
      gld_lds16(Bw + (size_t)(n0 + r) * Kd + k0 + ld_col, sB + ch * 512);
    }
    __syncthreads();
#pragma unroll
    for (int ks = 0; ks < 2; ++ks) {
      const int kk = ks * 32 + (lane >> 4) * 8;
      short8 a[4], b[4];
#pragma unroll
      for (int t = 0; t < 4; ++t) {
        a[t] = *(const short8*)(sA + (wm + t * 16 + (lane & 15)) * BK + kk);
        b[t] = *(const short8*)(sB + (wn + t * 16 + (lane & 15)) * BK + kk);
      }
#pragma unroll
      for (int mt = 0; mt < 4; ++mt)
#pragma unroll
        for (int nt = 0; nt < 4; ++nt)
          acc[mt][nt] = __builtin_amdgcn_mfma_f32_16x16x32_bf16(a[mt], b[nt], acc[mt][nt], 0, 0, 0);
    }
  }

  const int er = lane >> 4;   // C/D: row=(lane>>4)*4+reg, col=lane&15 (m89-verified)
  const int ec = lane & 15;
#pragma unroll
  for (int mt = 0; mt < 4; ++mt) {
#pragma unroll
    for (int nt = 0; nt < 4; ++nt) {
      const int col = n0 + wn + nt * 16 + ec;
      const float bv = HAS_BIAS ? bias[col] : 0.f;
#pragma unroll
      for (int r = 0; r < 4; ++r) {
        const int row = m0 + wm + mt * 16 + er * 4 + r;
        const float v = acc[mt][nt][r] + bv;
        if (OUT_BF16)
          ((unsigned short*)Cout)[(size_t)row * Nd + col] = f2bf(v);
        else
          ((float*)Cout)[(size_t)row * Nd + col] = v;
      }
    }
  }
}

static __device__ __forceinline__ void cswap64(unsigned long long& hi, unsigned long long& lo) {
  unsigned long long x = hi, y = lo;
  bool c = y > x;
  hi = c ? y : x;
  lo = c ? x : y;
}

static __device__ __forceinline__ unsigned long long topk_key(float val, int idx) {
  unsigned u = __float_as_uint(val);
  u ^= ((unsigned)((int)u >> 31)) | 0x80000000u;   // monotone order map
  return (((unsigned long long)u) << 32) | (unsigned long long)(0xFFFFFFFFu - (unsigned)idx);
}

// ================= prep: (topk + 2 convert units)/block + transposes + fused bias ============
// RULE (R0 + R8, twice-measured): never co-compile the 32KB-LDS GEMM body into this kernel.
// R9 diagnosis: prep ran at 1.6TB/s with nothing saturated — topk blocks idle their memory
// pipe during the ~600cy serial tau/extract phase while 16384 tiny convert blocks have no
// latency to hide. 16384 conv units / 8192 topk blocks = exactly 2: fold converts INTO the
// topk blocks so their streaming traffic drains under the topk serial phases.
// blocks [0,8192): topk row b (R5 algorithm, unchanged) + convert units 2b, 2b+1
// blocks [8192,8704): fp32->bf16 transpose of Wq_proj / Wp_proj (64x64 tiles)
// blocks [8704,9472): bc = W @ b_proj + b  (3 x 256 blocks, fp32)
#define PREP_BLOCKS 9472
struct PrepArgs {
  const float* cs[6]; unsigned short* cd[6];
  const float* ts[2]; unsigned short* td[2];
  const float* bW[3]; const float* bp[3]; const float* bb[3]; float* bo[3];
  const float* logits; int* topk;
};

__global__ __launch_bounds__(256) void prep_kernel(PrepArgs a) {
  const int b0 = blockIdx.x;
  if (b0 < 8192) {
    __shared__ float s_tau[4];
    __shared__ int s_cnt;
    __shared__ unsigned long long s_cand[128];
    const int row = b0;
    const int tid = threadIdx.x;
    const int wid = tid >> 6, lane = tid & 63;
    const float4* lp4 = (const float4*)(a.logits + (size_t)row * P_ROWS);

    if (tid == 0) s_cnt = 0;

    // issue logits loads first, then the 2 convert-unit loads (independent traffic that
    // drains during the serial phases below)
    float4 r0 = lp4[tid];
    float4 r1 = lp4[256 + tid];
    float4 r2 = lp4[512 + tid];
    float4 r3 = lp4[768 + tid];

    const float* csrc[2];
    unsigned short* cdst[2];
    unsigned coff[2];
#pragma unroll
    for (int q = 0; q < 2; ++q) {
      const int u = b0 * 2 + q;
      int seg; unsigned local;
      if (u < 8192) { seg = 0; local = (unsigned)u; }
      else if (u < 12288) { seg = 1; local = (unsigned)(u - 8192); }
      else { seg = 2 + ((u - 12288) >> 10); local = (unsigned)(u - 12288) & 1023u; }
      csrc[q] = a.cs[seg];
      cdst[q] = a.cd[seg];
      coff[q] = (local << 10) + (unsigned)tid * 4u;
    }
    float4 c0 = *(const float4*)(csrc[0] + coff[0]);
    float4 c1 = *(const float4*)(csrc[1] + coff[1]);

    // pass 1: thread-max of logits (consumes r0..r3)
    float tmax =
        fmaxf(fmaxf(fmaxf(fmaxf(r0.x, r0.y), fmaxf(r0.z, r0.w)),
                    fmaxf(fmaxf(r1.x, r1.y), fmaxf(r1.z, r1.w))),
              fmaxf(fmaxf(fmaxf(r2.x, r2.y), fmaxf(r2.z, r2.w)),
                    fmaxf(fmaxf(r3.x, r3.y), fmaxf(r3.z, r3.w))));

    // convert units: cvt + store (issues while tau chain runs below)
    {
      ushort4 o0, o1;
      o0.x = f2bf(c0.x); o0.y = f2bf(c0.y); o0.z = f2bf(c0.z); o0.w = f2bf(c0.w);
      o1.x = f2bf(c1.x); o1.y = f2bf(c1.y); o1.z = f2bf(c1.z); o1.w = f2bf(c1.w);
      *(ushort4*)(cdst[0] + coff[0]) = o0;
      *(ushort4*)(cdst[1] + coff[1]) = o1;
    }

    // per-wave tau = 6th-largest thread-max; block tau = max over waves (valid bound)
    float mkeep = tmax, tau = tmax;
#pragma unroll
    for (int it = 0; it < K_TOP; ++it) {
      float best = mkeep;
#pragma unroll
      for (int o = 32; o > 0; o >>= 1) best = fmaxf(best, __shfl_xor(best, o));
      tau = best;
      if (it < K_TOP - 1) mkeep = (mkeep == best) ? -1e38f : mkeep;
    }
    if (lane == 0) s_tau[wid] = tau;
    __syncthreads();
    tau = fmaxf(fmaxf(s_tau[0], s_tau[1]), fmaxf(s_tau[2], s_tau[3]));

    // pass 2: only lanes that can hold a candidate re-read (rare, L1/L2-hit)
    if (tmax >= tau) {
      float4 q0 = lp4[tid];
      float4 q1 = lp4[256 + tid];
      float4 q2 = lp4[512 + tid];
      float4 q3 = lp4[768 + tid];
      auto push = [&](float v, int idx) {
        if (v >= tau) {
          int s = atomicAdd(&s_cnt, 1);
          if (s < 128) s_cand[s] = topk_key(v, idx);
        }
      };
      const int e0 = tid * 4, e1 = 1024 + tid * 4, e2 = 2048 + tid * 4, e3 = 3072 + tid * 4;
      push(q0.x, e0); push(q0.y, e0 + 1); push(q0.z, e0 + 2); push(q0.w, e0 + 3);
      push(q1.x, e1); push(q1.y, e1 + 1); push(q1.z, e1 + 2); push(q1.w, e1 + 3);
      push(q2.x, e2); push(q2.y, e2 + 1); push(q2.z, e2 + 2); push(q2.w, e2 + 3);
      push(q3.x, e3); push(q3.y, e3 + 1); push(q3.z, e3 + 2); push(q3.w, e3 + 3);
    }
    __syncthreads();
    const int n = s_cnt;
    if (wid != 0) return;

    if (n <= 128) {
      unsigned long long k0 = (lane < n) ? s_cand[lane] : 0ull;
      unsigned long long k1 = (lane + 64 < n) ? s_cand[lane + 64] : 0ull;
#pragma unroll
      for (int it = 0; it < K_TOP; ++it) {
        unsigned long long best = k0 > k1 ? k0 : k1;
#pragma unroll
        for (int o = 32; o > 0; o >>= 1) {
          unsigned long long t = __shfl_xor(best, o);
          best = t > best ? t : best;
        }
        if (lane == 0)
          a.topk[row * K_TOP + it] = (int)(0xFFFFFFFFu - (unsigned)(best & 0xFFFFFFFFull));
        k0 = (k0 == best) ? 0ull : k0;   // keys distinct (idx in key) -> removes exactly one
        k1 = (k1 == best) ? 0ull : k1;
      }
    } else {
      // exact fallback (unreachable in practice): wave 0 re-reads row, streaming insert
      unsigned long long m0 = 0, m1 = 0, m2 = 0, m3 = 0, m4 = 0, m5 = 0;
      auto ins = [&](float val, int idx) {
        unsigned long long key = topk_key(val, idx);
        m5 = key > m5 ? key : m5;
        cswap64(m4, m5);
        cswap64(m3, m4);
        cswap64(m2, m3);
        cswap64(m1, m2);
        cswap64(m0, m1);
      };
      for (int j = 0; j < 16; ++j) {
        float4 v = lp4[j * 64 + lane];
        const int base = j * 256 + lane * 4;
        ins(v.x, base);
        ins(v.y, base + 1);
        ins(v.z, base + 2);
        ins(v.w, base + 3);
      }
#pragma unroll
      for (int it = 0; it < K_TOP; ++it) {
        unsigned long long best = m0;
#pragma unroll
        for (int o = 32; o > 0; o >>= 1) {
          unsigned long long t = __shfl_xor(best, o);
          best = t > best ? t : best;
        }
        if (lane == 0)
          a.topk[row * K_TOP + it] = (int)(0xFFFFFFFFu - (unsigned)(best & 0xFFFFFFFFull));
        const bool pred = (m0 == best);
        m0 = pred ? m1 : m0;
        m1 = pred ? m2 : m1;
        m2 = pred ? m3 : m2;
        m3 = pred ? m4 : m3;
        m4 = pred ? m5 : m4;
        m5 = pred ? 0ull : m5;
      }
    }
    return;
  }
  const int b = b0 - 8192;
  if (b < 512) {
    __shared__ unsigned short t[64][72];
    const int which = b >> 8;
    const int tile = b & 255;
    const int i0 = (tile >> 4) * 64, j0 = (tile & 15) * 64;
    const float* src = a.ts[which];
    unsigned short* dst = a.td[which];
    const int r = threadIdx.x >> 4;
    const int c = (threadIdx.x & 15) * 4;
#pragma unroll
    for (int rr = 0; rr < 4; ++rr) {
      const int row = r + rr * 16;
      float4 v = *(const float4*)(src + (size_t)(i0 + row) * D_DIM + j0 + c);
      t[c + 0][row] = f2bf(v.x); t[c + 1][row] = f2bf(v.y);
      t[c + 2][row] = f2bf(v.z); t[c + 3][row] = f2bf(v.w);
    }
    __syncthreads();
#pragma unroll
    for (int rr = 0; rr < 4; ++rr) {
      const int row = r + rr * 16;
      ushort4 v = *(const ushort4*)(&t[row][c]);
      *(ushort4*)(dst + (size_t)(j0 + row) * D_DIM + i0 + c) = v;
    }
  } else {
    const int b3 = b - 512;
    const int j = b3 >> 8;
    const int nb = b3 & 255;
    const int wid = threadIdx.x >> 6, lane = threadIdx.x & 63;
    const int n = nb * 4 + wid;
    const float* W = a.bW[j] + (size_t)n * D_DIM;
    const float* p = a.bp[j];
    float s = 0.f;
#pragma unroll
    for (int d = lane; d < D_DIM; d += 64) s += W[d] * p[d];
#pragma unroll
    for (int o = 32; o > 0; o >>= 1) s += __shfl_xor(s, o);
    if (lane == 0) a.bo[j][n] = s + a.bb[j][n];
  }
}

// ================= Phase B: weight-fusion GEMMs only (MFMA) =================
// blocks [0,192): Wc = Wx @ WprojT (3 x 64 tiles, no bias)
#define MID_BLOCKS 192
struct MidArgs {
  const unsigned short* fA[3]; const unsigned short* fW[3]; unsigned short* fC[3];
};

__global__ __launch_bounds__(256) void mid_kernel(MidArgs a) {
  const int z = blockIdx.x >> 6;
  const int tile = blockIdx.x & 63;
  gemm_bt_body<true, false>(a.fA[z], a.fW[z], nullptr, (void*)a.fC[z],
                            (tile >> 3) * 128, (tile & 7) * 128);
}

// ================= Phase C: three production GEMMs, XCD-chunked tile mapping =================
// blocks [0,512): q2 (M=8192); [512,768): kb (M=4096); [768,1024): vb
// T1: default round-robin puts 8 consecutive blocks (same A-panel) on 8 XCDs -> A-panel
// HBM-fetched once per XCD. Bijective chunk map (nwg%8==0 for all segs) gives each XCD a
// contiguous m-chunk -> A read ~once.
#define GEMM3_BLOCKS 1024
struct Gemm3Args {
  const unsigned short* A[3]; const unsigned short* W[3]; const float* bias[3];
  unsigned short* C[3];
};

__global__ __launch_bounds__(256) void gemm3_kernel(Gemm3Args a) {
  const int b = blockIdx.x;
  int seg, lb, cpx;
  if (b < 512) { seg = 0; lb = b; cpx = 64; }
  else if (b < 768) { seg = 1; lb = b - 512; cpx = 32; }
  else { seg = 2; lb = b - 768; cpx = 32; }
  const int t = (lb & 7) * cpx + (lb >> 3);
  gemm_bt_body<true, true>(a.A[seg], a.W[seg], a.bias[seg], (void*)a.C[seg],
                           (t >> 3) * 128, (t & 7) * 128);
}

// ================= Phase E: context = ctx @ Wo^T + bo (fp32 out), XCD-chunked ==============
__global__ __launch_bounds__(256) void gemm_o_kernel(
    const unsigned short* __restrict__ A, const unsigned short* __restrict__ Bw,
    const float* __restrict__ bias, float* __restrict__ Cout) {
  const int b = blockIdx.x;
  const int t = (b & 7) * 64 + (b >> 3);
  gemm_bt_body<false, true>(A, Bw, bias, (void*)Cout, (t >> 3) * 128, (t & 7) * 128);
}

// ================= attention: one WAVE per row, 16-byte vector loads =================
// Lane l, chunk c in {0,1} holds dims [c*512 + l*8, +8). One head's 64 dims = 8
// consecutive lanes of one chunk -> QK reduce = 3-level shfl_xor within 8-lane groups,
// all 16 heads in parallel. Two per-lane softmaxes (head l/8 and head 8+l/8).
__global__ __launch_bounds__(256) void attn_kernel(
    const unsigned short* __restrict__ q2,
    const unsigned short* __restrict__ kb,
    const unsigned short* __restrict__ vb,
    const int* __restrict__ topk,
    unsigned short* __restrict__ ctx,
    float* __restrict__ attnw) {
  const int wid = threadIdx.x >> 6, lane = threadIdx.x & 63;
  const int b = blockIdx.x * 4 + wid;

  int idx[K_TOP];
#pragma unroll
  for (int j = 0; j < K_TOP; ++j) idx[j] = topk[b * K_TOP + j];

  const short8* q2r = (const short8*)(q2 + (size_t)b * D_DIM);
  short8 qv0 = q2r[lane], qv1 = q2r[64 + lane];
  float q0[8], q1[8];
#pragma unroll
  for (int i = 0; i < 8; ++i) {
    q0[i] = bf2f((unsigned short)qv0[i]);
    q1[i] = bf2f((unsigned short)qv1[i]);
  }

  float s0[K_TOP], s1[K_TOP];
#pragma unroll
  for (int j = 0; j < K_TOP; ++j) {
    const short8* kr = (const short8*)(kb + (size_t)idx[j] * D_DIM);
    short8 k0 = kr[lane], k1 = kr[64 + lane];
    float p0 = 0.f, p1 = 0.f;
#pragma unroll
    for (int i = 0; i < 8; ++i) {
      p0 += q0[i] * bf2f((unsigned short)k0[i]);
      p1 += q1[i] * bf2f((unsigned short)k1[i]);
    }
    s0[j] = p0; s1[j] = p1;
  }
#pragma unroll
  for (int j = 0; j < K_TOP; ++j) {
#pragma unroll
    for (int o = 1; o < 8; o <<= 1) {
      s0[j] += __shfl_xor(s0[j], o);
      s1[j] += __shfl_xor(s1[j], o);
    }
  }

  float mx0 = -1e30f, mx1 = -1e30f;
#pragma unroll
  for (int j = 0; j < K_TOP; ++j) {
    mx0 = fmaxf(mx0, s0[j] * 0.125f);
    mx1 = fmaxf(mx1, s1[j] * 0.125f);
  }
  float w0[K_TOP], w1[K_TOP], sum0 = 0.f, sum1 = 0.f;
#pragma unroll
  for (int j = 0; j < K_TOP; ++j) {
    w0[j] = __expf(s0[j] * 0.125f - mx0); sum0 += w0[j];
    w1[j] = __expf(s1[j] * 0.125f - mx1); sum1 += w1[j];
  }
  const float inv0 = 1.0f / sum0, inv1 = 1.0f / sum1;
#pragma unroll
  for (int j = 0; j < K_TOP; ++j) { w0[j] *= inv0; w1[j] *= inv1; }

  float o0[8], o1[8];
#pragma unroll
  for (int i = 0; i < 8; ++i) { o0[i] = 0.f; o1[i] = 0.f; }
#pragma unroll
  for (int j = 0; j < K_TOP; ++j) {
    const short8* vr = (const short8*)(vb + (size_t)idx[j] * D_DIM);
    short8 v0 = vr[lane], v1 = vr[64 + lane];
#pragma unroll
    for (int i = 0; i < 8; ++i) {
      o0[i] += w0[j] * bf2f((unsigned short)v0[i]);
      o1[i] += w1[j] * bf2f((unsigned short)v1[i]);
    }
  }
  short8 c0, c1;
#pragma unroll
  for (int i = 0; i < 8; ++i) {
    c0[i] = (short)f2bf(o0[i]);
    c1[i] = (short)f2bf(o1[i]);
  }
  short8* cr = (short8*)(ctx + (size_t)b * D_DIM);
  cr[lane] = c0;
  cr[64 + lane] = c1;

  // attn_weights: mean over 16 heads. Each 8-lane group holds identical (w0,w1) for
  // its 2 heads -> full-wave sum counts each head 8x -> divide by 8*16 = 128.
  float t[K_TOP];
#pragma unroll
  for (int j = 0; j < K_TOP; ++j) t[j] = w0[j] + w1[j];
#pragma unroll
  for (int j = 0; j < K_TOP; ++j)
#pragma unroll
    for (int o = 32; o > 0; o >>= 1) t[j] += __shfl_xor(t[j], o);
  if (lane == 0) {
#pragma unroll
    for (int j = 0; j < K_TOP; ++j)
      attnw[(size_t)b * K_TOP + j] = t[j] * (1.0f / 128.0f);
  }
}

extern "C" void kernel_launch(void* const* d_in, const int* in_sizes, int n_in,
                              void* d_out, int out_size, void* d_ws, size_t ws_size,
                              hipStream_t stream) {
  const float* query   = (const float*)d_in[0];
  const float* bank    = (const float*)d_in[1];
  const float* logits  = (const float*)d_in[2];
  const float* Wq_proj = (const float*)d_in[3];
  const float* bq_proj = (const float*)d_in[4];
  const float* Wp_proj = (const float*)d_in[5];
  const float* bp_proj = (const float*)d_in[6];
  const float* Wq      = (const float*)d_in[7];
  const float* bq      = (const float*)d_in[8];
  const float* Wk      = (const float*)d_in[9];
  const float* bk      = (const float*)d_in[10];
  const float* Wv      = (const float*)d_in[11];
  const float* bv      = (const float*)d_in[12];
  const float* Wo      = (const float*)d_in[13];
  const float* bo      = (const float*)d_in[14];

  char* ws = (char*)d_ws;
  size_t off = 0;
  auto alloc = [&](size_t bytes) {
    void* p = ws + off;
    off += (bytes + 255) & ~(size_t)255;
    return p;
  };
  unsigned short* q_bf    = (unsigned short*)alloc((size_t)B_ROWS * D_DIM * 2); // query, then ctx
  unsigned short* bank_bf = (unsigned short*)alloc((size_t)P_ROWS * D_DIM * 2);
  unsigned short* q2_bf   = (unsigned short*)alloc((size_t)B_ROWS * D_DIM * 2);
  unsigned short* kb_bf   = (unsigned short*)alloc((size_t)P_ROWS * D_DIM * 2);
  unsigned short* vb_bf   = (unsigned short*)alloc((size_t)P_ROWS * D_DIM * 2);
  unsigned short* wq_bf   = (unsigned short*)alloc((size_t)D_DIM * D_DIM * 2);
  unsigned short* wk_bf   = (unsigned short*)alloc((size_t)D_DIM * D_DIM * 2);
  unsigned short* wv_bf   = (unsigned short*)alloc((size_t)D_DIM * D_DIM * 2);
  unsigned short* wo_bf   = (unsigned short*)alloc((size_t)D_DIM * D_DIM * 2);
  unsigned short* wqpT_bf = (unsigned short*)alloc((size_t)D_DIM * D_DIM * 2);
  unsigned short* wppT_bf = (unsigned short*)alloc((size_t)D_DIM * D_DIM * 2);
  unsigned short* wcq_bf  = (unsigned short*)alloc((size_t)D_DIM * D_DIM * 2);
  unsigned short* wck_bf  = (unsigned short*)alloc((size_t)D_DIM * D_DIM * 2);
  unsigned short* wcv_bf  = (unsigned short*)alloc((size_t)D_DIM * D_DIM * 2);
  float* bcq              = (float*)alloc(D_DIM * 4);
  float* bck              = (float*)alloc(D_DIM * 4);
  float* bcv              = (float*)alloc(D_DIM * 4);
  int* topk               = (int*)alloc((size_t)B_ROWS * K_TOP * 4);

  float* out_ctx  = (float*)d_out;
  float* out_attn = out_ctx + (size_t)B_ROWS * D_DIM;
  (void)out_ctx;

  // Phase A: (top-k + converts)/block + transposes + biases
  PrepArgs pa;
  pa.cs[0] = query; pa.cd[0] = q_bf;
  pa.cs[1] = bank;  pa.cd[1] = bank_bf;
  pa.cs[2] = Wq;    pa.cd[2] = wq_bf;
  pa.cs[3] = Wk;    pa.cd[3] = wk_bf;
  pa.cs[4] = Wv;    pa.cd[4] = wv_bf;
  pa.cs[5] = Wo;    pa.cd[5] = wo_bf;
  pa.ts[0] = Wq_proj; pa.td[0] = wqpT_bf;
  pa.ts[1] = Wp_proj; pa.td[1] = wppT_bf;
  pa.bW[0] = Wq; pa.bp[0] = bq_proj; pa.bb[0] = bq; pa.bo[0] = bcq;
  pa.bW[1] = Wk; pa.bp[1] = bp_proj; pa.bb[1] = bk; pa.bo[1] = bck;
  pa.bW[2] = Wv; pa.bp[2] = bp_proj; pa.bb[2] = bv; pa.bo[2] = bcv;
  pa.logits = logits; pa.topk = topk;
  prep_kernel<<<PREP_BLOCKS, 256, 0, stream>>>(pa);

  // Phase B: weight-fusion GEMMs (small)
  MidArgs ma;
  ma.fA[0] = wq_bf; ma.fW[0] = wqpT_bf; ma.fC[0] = wcq_bf;
  ma.fA[1] = wk_bf; ma.fW[1] = wppT_bf; ma.fC[1] = wck_bf;
  ma.fA[2] = wv_bf; ma.fW[2] = wppT_bf; ma.fC[2] = wcv_bf;
  mid_kernel<<<MID_BLOCKS, 256, 0, stream>>>(ma);

  // Phase C: q2 + kb + vb GEMMs in one launch (XCD-chunked)
  Gemm3Args ga;
  ga.A[0] = q_bf;    ga.W[0] = wcq_bf; ga.bias[0] = bcq; ga.C[0] = q2_bf;
  ga.A[1] = bank_bf; ga.W[1] = wck_bf; ga.bias[1] = bck; ga.C[1] = kb_bf;
  ga.A[2] = bank_bf; ga.W[2] = wcv_bf; ga.bias[2] = bcv; ga.C[2] = vb_bf;
  gemm3_kernel<<<GEMM3_BLOCKS, 256, 0, stream>>>(ga);

  // Phase D: attention (ctx overwrites q_bf, which is free now); one wave per row
  attn_kernel<<<B_ROWS / 4, 256, 0, stream>>>(q2_bf, kb_bf, vb_bf, topk, q_bf, out_attn);

  // Phase E: context = ctx @ Wo^T + bo (fp32 out, XCD-chunked)
  gemm_o_kernel<<<512, 256, 0, stream>>>(q_bf, wo_bf, bo, (float*)d_out);
}

// Round 11
// 400.418 us; speedup vs baseline: 1.0167x; 1.0167x over previous
//
#include <hip/hip_runtime.h>
#include <stdint.h>

#define B_ROWS 8192
#define P_ROWS 4096
#define D_DIM  1024
#define K_TOP  6

typedef __attribute__((ext_vector_type(8))) short short8;
typedef __attribute__((ext_vector_type(4))) float floatx4;

static __device__ __forceinline__ float bf2f(unsigned short h) {
  return __uint_as_float(((unsigned)h) << 16);
}
static __device__ __forceinline__ unsigned short f2bf(float f) {
  unsigned u = __float_as_uint(f);
  u += 0x7FFFu + ((u >> 16) & 1u);   // RNE
  return (unsigned short)(u >> 16);
}

// ---------------- bf16 MFMA GEMM body, C[m,n] = sum_d A[m,d]*W[n,d] (+ bias[n]) ----------------
typedef __attribute__((address_space(3))) unsigned int lds32_t;
typedef const __attribute__((address_space(1))) unsigned int g32_t;

static __device__ __forceinline__ void gld_lds16(const unsigned short* g, unsigned short* l) {
  __builtin_amdgcn_global_load_lds((g32_t*)(uintptr_t)g,
                                   (lds32_t*)(unsigned int)(uintptr_t)l, 16, 0, 0);
}

template <bool OUT_BF16, bool HAS_BIAS>
static __device__ __forceinline__ void gemm_bt_body(
    const unsigned short* __restrict__ A, const unsigned short* __restrict__ Bw,
    const float* __restrict__ bias, void* __restrict__ Cout, int m0, int n0) {
  constexpr int Kd = 1024, Nd = 1024, BK = 64;
  __shared__ unsigned short sA[128 * BK];
  __shared__ unsigned short sB[128 * BK];

  const int tid = threadIdx.x;
  const int wid = tid >> 6, lane = tid & 63;
  const int wm = (wid & 1) * 64, wn = (wid >> 1) * 64;

  floatx4 acc[4][4];
#pragma unroll
  for (int mt = 0; mt < 4; ++mt)
#pragma unroll
    for (int nt = 0; nt < 4; ++nt) acc[mt][nt] = (floatx4){0.f, 0.f, 0.f, 0.f};

  const int ld_row = lane >> 3;
  const int ld_col = (lane & 7) * 8;

  for (int kt = 0; kt < Kd / BK; ++kt) {
    const int k0 = kt * BK;
    __syncthreads();
#pragma unroll
    for (int c = 0; c < 4; ++c) {
      const int ch = wid * 4 + c;
      const int r = ch * 8 + ld_row;
      gld_lds16(A  + (size_t)(m0 + r) * Kd + k0 + ld_col, sA + ch * 512);
      gld_lds16(Bw + (size_t)(n0 + r) * Kd + k0 + ld_col, sB + ch * 512);
    }
    __syncthreads();
#pragma unroll
    for (int ks = 0; ks < 2; ++ks) {
      const int kk = ks * 32 + (lane >> 4) * 8;
      short8 a[4], b[4];
#pragma unroll
      for (int t = 0; t < 4; ++t) {
        a[t] = *(const short8*)(sA + (wm + t * 16 + (lane & 15)) * BK + kk);
        b[t] = *(const short8*)(sB + (wn + t * 16 + (lane & 15)) * BK + kk);
      }
#pragma unroll
      for (int mt = 0; mt < 4; ++mt)
#pragma unroll
        for (int nt = 0; nt < 4; ++nt)
          acc[mt][nt] = __builtin_amdgcn_mfma_f32_16x16x32_bf16(a[mt], b[nt], acc[mt][nt], 0, 0, 0);
    }
  }

  const int er = lane >> 4;   // C/D: row=(lane>>4)*4+reg, col=lane&15 (m89-verified)
  const int ec = lane & 15;
#pragma unroll
  for (int mt = 0; mt < 4; ++mt) {
#pragma unroll
    for (int nt = 0; nt < 4; ++nt) {
      const int col = n0 + wn + nt * 16 + ec;
      const float bv = HAS_BIAS ? bias[col] : 0.f;
#pragma unroll
      for (int r = 0; r < 4; ++r) {
        const int row = m0 + wm + mt * 16 + er * 4 + r;
        const float v = acc[mt][nt][r] + bv;
        if (OUT_BF16)
          ((unsigned short*)Cout)[(size_t)row * Nd + col] = f2bf(v);
        else
          ((float*)Cout)[(size_t)row * Nd + col] = v;
      }
    }
  }
}

static __device__ __forceinline__ void cswap64(unsigned long long& hi, unsigned long long& lo) {
  unsigned long long x = hi, y = lo;
  bool c = y > x;
  hi = c ? y : x;
  lo = c ? x : y;
}

static __device__ __forceinline__ unsigned long long topk_key(float val, int idx) {
  unsigned u = __float_as_uint(val);
  u ^= ((unsigned)((int)u >> 31)) | 0x80000000u;   // monotone order map
  return (((unsigned long long)u) << 32) | (unsigned long long)(0xFFFFFFFFu - (unsigned)idx);
}

// compare-exchange: x=max, y=min
static __device__ __forceinline__ void cef(float& x, float& y) {
  float mx = fmaxf(x, y);
  y = fminf(x, y);
  x = mx;
}
static __device__ __forceinline__ void ceu(unsigned long long& x, unsigned long long& y) {
  unsigned long long a = x, b = y;
  bool c = b > a;
  x = c ? b : a;
  y = c ? a : b;
}

// ================= prep: topk + conv6 + transposed-convert(Wqp,Wpp) + fused bias ============
// RULE (R0 + R8, twice-measured): never co-compile the 32KB-LDS GEMM body into this kernel.
// RULE (R10): don't interleave convert traffic into topk blocks — it evicts the logits row
// between pass1 and pass2 (+18MB FETCH, net negative).
// R10 cycle accounting: topk cost is DEPENDENT shfl chains (DS-pipe ~120cy each): old tau =
// 36 dep ops (~4.3k cy), old extraction = 72 dep ops on wave 0 ALONE (~8.6k cy tail). Fix:
// butterfly sorted-8-list bitonic merge — 6 dep rounds total for tau, 6 for extraction.
// blocks [0,8192): exact threshold-filtered top-6, one block per row
// blocks [8192,24576): fp32->bf16 convert {query 8192, bank 4096, Wq/Wk/Wv/Wo 1024 each}
// blocks [24576,25088): fp32->bf16 transpose of Wq_proj / Wp_proj (64x64 tiles)
// blocks [25088,25856): bc = W @ b_proj + b  (3 x 256 blocks, fp32)
#define PREP_BLOCKS 25856
struct PrepArgs {
  const float* cs[6]; unsigned short* cd[6];
  const float* ts[2]; unsigned short* td[2];
  const float* bW[3]; const float* bp[3]; const float* bb[3]; float* bo[3];
  const float* logits; int* topk;
};

__global__ __launch_bounds__(256) void prep_kernel(PrepArgs a) {
  const int b0 = blockIdx.x;
  if (b0 < 8192) {
    __shared__ float s_tau[4];
    __shared__ int s_cnt;
    __shared__ unsigned long long s_cand[128];
    const int row = b0;
    const int tid = threadIdx.x;
    const int wid = tid >> 6, lane = tid & 63;
    const float4* lp4 = (const float4*)(a.logits + (size_t)row * P_ROWS);

    if (tid == 0) s_cnt = 0;

    // pass 1: thread-max only; loads consumed immediately
    float4 r0 = lp4[tid];
    float4 r1 = lp4[256 + tid];
    float4 r2 = lp4[512 + tid];
    float4 r3 = lp4[768 + tid];
    float tmax =
        fmaxf(fmaxf(fmaxf(fmaxf(r0.x, r0.y), fmaxf(r0.z, r0.w)),
                    fmaxf(fmaxf(r1.x, r1.y), fmaxf(r1.z, r1.w))),
              fmaxf(fmaxf(fmaxf(r2.x, r2.y), fmaxf(r2.z, r2.w)),
                    fmaxf(fmaxf(r3.x, r3.y), fmaxf(r3.z, r3.w))));

    // tau: butterfly sorted-8 bitonic merge over the wave (6 dependent rounds).
    // After the loop every lane holds the wave's exact top-8 thread-maxes, descending.
    float L[8];
    L[0] = tmax;
#pragma unroll
    for (int i = 1; i < 8; ++i) L[i] = -1e38f;
#pragma unroll
    for (int d = 1; d < 64; d <<= 1) {
      float Bv[8];
#pragma unroll
      for (int i = 0; i < 8; ++i) Bv[i] = __shfl_xor(L[i], d);   // independent fetches
      float C[8];
#pragma unroll
      for (int i = 0; i < 8; ++i) C[i] = fmaxf(L[i], Bv[7 - i]); // bitonic half-cleaner
      cef(C[0], C[4]); cef(C[1], C[5]); cef(C[2], C[6]); cef(C[3], C[7]);
      cef(C[0], C[2]); cef(C[1], C[3]); cef(C[4], C[6]); cef(C[5], C[7]);
      cef(C[0], C[1]); cef(C[2], C[3]); cef(C[4], C[5]); cef(C[6], C[7]);
#pragma unroll
      for (int i = 0; i < 8; ++i) L[i] = C[i];
    }
    float tau = L[5];   // exact per-wave 6th-largest thread-max (valid bound)
    if (lane == 0) s_tau[wid] = tau;
    __syncthreads();
    tau = fmaxf(fmaxf(s_tau[0], s_tau[1]), fmaxf(s_tau[2], s_tau[3]));

    // pass 2: only lanes that can hold a candidate re-read (rare, L1/L2-hit)
    if (tmax >= tau) {
      float4 q0 = lp4[tid];
      float4 q1 = lp4[256 + tid];
      float4 q2 = lp4[512 + tid];
      float4 q3 = lp4[768 + tid];
      auto push = [&](float v, int idx) {
        if (v >= tau) {
          int s = atomicAdd(&s_cnt, 1);
          if (s < 128) s_cand[s] = topk_key(v, idx);
        }
      };
      const int e0 = tid * 4, e1 = 1024 + tid * 4, e2 = 2048 + tid * 4, e3 = 3072 + tid * 4;
      push(q0.x, e0); push(q0.y, e0 + 1); push(q0.z, e0 + 2); push(q0.w, e0 + 3);
      push(q1.x, e1); push(q1.y, e1 + 1); push(q1.z, e1 + 2); push(q1.w, e1 + 3);
      push(q2.x, e2); push(q2.y, e2 + 1); push(q2.z, e2 + 2); push(q2.w, e2 + 3);
      push(q3.x, e3); push(q3.y, e3 + 1); push(q3.z, e3 + 2); push(q3.w, e3 + 3);
    }
    __syncthreads();
    const int n = s_cnt;
    if (wid != 0) return;

    if (n <= 128) {
      // extraction: butterfly sorted-8 u64 merge (6 dependent rounds, all lanes of wave 0).
      unsigned long long k0 = (lane < n) ? s_cand[lane] : 0ull;
      unsigned long long k1 = (lane + 64 < n) ? s_cand[lane + 64] : 0ull;
      unsigned long long U[8];
      U[0] = k0 > k1 ? k0 : k1;
      U[1] = k0 > k1 ? k1 : k0;
#pragma unroll
      for (int i = 2; i < 8; ++i) U[i] = 0ull;
#pragma unroll
      for (int d = 1; d < 64; d <<= 1) {
        unsigned long long Bv[8];
#pragma unroll
        for (int i = 0; i < 8; ++i) Bv[i] = __shfl_xor(U[i], d);
        unsigned long long C[8];
#pragma unroll
        for (int i = 0; i < 8; ++i) C[i] = U[i] > Bv[7 - i] ? U[i] : Bv[7 - i];
        ceu(C[0], C[4]); ceu(C[1], C[5]); ceu(C[2], C[6]); ceu(C[3], C[7]);
        ceu(C[0], C[2]); ceu(C[1], C[3]); ceu(C[4], C[6]); ceu(C[5], C[7]);
        ceu(C[0], C[1]); ceu(C[2], C[3]); ceu(C[4], C[5]); ceu(C[6], C[7]);
#pragma unroll
        for (int i = 0; i < 8; ++i) U[i] = C[i];
      }
      if (lane == 0) {
#pragma unroll
        for (int it = 0; it < K_TOP; ++it)
          a.topk[row * K_TOP + it] = (int)(0xFFFFFFFFu - (unsigned)(U[it] & 0xFFFFFFFFull));
      }
    } else {
      // exact fallback (unreachable in practice): wave 0 re-reads row, streaming insert
      unsigned long long m0 = 0, m1 = 0, m2 = 0, m3 = 0, m4 = 0, m5 = 0;
      auto ins = [&](float val, int idx) {
        unsigned long long key = topk_key(val, idx);
        m5 = key > m5 ? key : m5;
        cswap64(m4, m5);
        cswap64(m3, m4);
        cswap64(m2, m3);
        cswap64(m1, m2);
        cswap64(m0, m1);
      };
      for (int j = 0; j < 16; ++j) {
        float4 v = lp4[j * 64 + lane];
        const int base = j * 256 + lane * 4;
        ins(v.x, base);
        ins(v.y, base + 1);
        ins(v.z, base + 2);
        ins(v.w, base + 3);
      }
#pragma unroll
      for (int it = 0; it < K_TOP; ++it) {
        unsigned long long best = m0;
#pragma unroll
        for (int o = 32; o > 0; o >>= 1) {
          unsigned long long t = __shfl_xor(best, o);
          best = t > best ? t : best;
        }
        if (lane == 0)
          a.topk[row * K_TOP + it] = (int)(0xFFFFFFFFu - (unsigned)(best & 0xFFFFFFFFull));
        const bool pred = (m0 == best);
        m0 = pred ? m1 : m0;
        m1 = pred ? m2 : m1;
        m2 = pred ? m3 : m2;
        m3 = pred ? m4 : m3;
        m4 = pred ? m5 : m4;
        m5 = pred ? 0ull : m5;
      }
    }
    return;
  }
  const int b = b0 - 8192;
  if (b < 16384) {
    int seg; unsigned sb;
    if (b < 8192) { seg = 0; sb = 0; }
    else if (b < 12288) { seg = 1; sb = 8192; }
    else { seg = 2 + ((b - 12288) >> 10); sb = 12288u + (((unsigned)(seg - 2)) << 10); }
    const unsigned off = (((unsigned)b - sb) << 10) + threadIdx.x * 4u;
    float4 v = *(const float4*)(a.cs[seg] + off);
    ushort4 o;
    o.x = f2bf(v.x); o.y = f2bf(v.y); o.z = f2bf(v.z); o.w = f2bf(v.w);
    *(ushort4*)(a.cd[seg] + off) = o;
  } else if (b < 16896) {
    __shared__ unsigned short t[64][72];
    const int tt = b - 16384;
    const int which = tt >> 8;
    const int tile = tt & 255;
    const int i0 = (tile >> 4) * 64, j0 = (tile & 15) * 64;
    const float* src = a.ts[which];
    unsigned short* dst = a.td[which];
    const int r = threadIdx.x >> 4;
    const int c = (threadIdx.x & 15) * 4;
#pragma unroll
    for (int rr = 0; rr < 4; ++rr) {
      const int row = r + rr * 16;
      float4 v = *(const float4*)(src + (size_t)(i0 + row) * D_DIM + j0 + c);
      t[c + 0][row] = f2bf(v.x); t[c + 1][row] = f2bf(v.y);
      t[c + 2][row] = f2bf(v.z); t[c + 3][row] = f2bf(v.w);
    }
    __syncthreads();
#pragma unroll
    for (int rr = 0; rr < 4; ++rr) {
      const int row = r + rr * 16;
      ushort4 v = *(const ushort4*)(&t[row][c]);
      *(ushort4*)(dst + (size_t)(j0 + row) * D_DIM + i0 + c) = v;
    }
  } else {
    const int b3 = b - 16896;
    const int j = b3 >> 8;
    const int nb = b3 & 255;
    const int wid = threadIdx.x >> 6, lane = threadIdx.x & 63;
    const int n = nb * 4 + wid;
    const float* W = a.bW[j] + (size_t)n * D_DIM;
    const float* p = a.bp[j];
    float s = 0.f;
#pragma unroll
    for (int d = lane; d < D_DIM; d += 64) s += W[d] * p[d];
#pragma unroll
    for (int o = 32; o > 0; o >>= 1) s += __shfl_xor(s, o);
    if (lane == 0) a.bo[j][n] = s + a.bb[j][n];
  }
}

// ================= Phase B: weight-fusion GEMMs only (MFMA) =================
// blocks [0,192): Wc = Wx @ WprojT (3 x 64 tiles, no bias)
#define MID_BLOCKS 192
struct MidArgs {
  const unsigned short* fA[3]; const unsigned short* fW[3]; unsigned short* fC[3];
};

__global__ __launch_bounds__(256) void mid_kernel(MidArgs a) {
  const int z = blockIdx.x >> 6;
  const int tile = blockIdx.x & 63;
  gemm_bt_body<true, false>(a.fA[z], a.fW[z], nullptr, (void*)a.fC[z],
                            (tile >> 3) * 128, (tile & 7) * 128);
}

// ================= Phase C: three production GEMMs, XCD-chunked tile mapping =================
// blocks [0,512): q2 (M=8192); [512,768): kb (M=4096); [768,1024): vb
#define GEMM3_BLOCKS 1024
struct Gemm3Args {
  const unsigned short* A[3]; const unsigned short* W[3]; const float* bias[3];
  unsigned short* C[3];
};

__global__ __launch_bounds__(256) void gemm3_kernel(Gemm3Args a) {
  const int b = blockIdx.x;
  int seg, lb, cpx;
  if (b < 512) { seg = 0; lb = b; cpx = 64; }
  else if (b < 768) { seg = 1; lb = b - 512; cpx = 32; }
  else { seg = 2; lb = b - 768; cpx = 32; }
  const int t = (lb & 7) * cpx + (lb >> 3);
  gemm_bt_body<true, true>(a.A[seg], a.W[seg], a.bias[seg], (void*)a.C[seg],
                           (t >> 3) * 128, (t & 7) * 128);
}

// ================= Phase E: context = ctx @ Wo^T + bo (fp32 out), XCD-chunked ==============
__global__ __launch_bounds__(256) void gemm_o_kernel(
    const unsigned short* __restrict__ A, const unsigned short* __restrict__ Bw,
    const float* __restrict__ bias, float* __restrict__ Cout) {
  const int b = blockIdx.x;
  const int t = (b & 7) * 64 + (b >> 3);
  gemm_bt_body<false, true>(A, Bw, bias, (void*)Cout, (t >> 3) * 128, (t & 7) * 128);
}

// ================= attention: one WAVE per row, 16-byte vector loads =================
__global__ __launch_bounds__(256) void attn_kernel(
    const unsigned short* __restrict__ q2,
    const unsigned short* __restrict__ kb,
    const unsigned short* __restrict__ vb,
    const int* __restrict__ topk,
    unsigned short* __restrict__ ctx,
    float* __restrict__ attnw) {
  const int wid = threadIdx.x >> 6, lane = threadIdx.x & 63;
  const int b = blockIdx.x * 4 + wid;

  int idx[K_TOP];
#pragma unroll
  for (int j = 0; j < K_TOP; ++j) idx[j] = topk[b * K_TOP + j];

  const short8* q2r = (const short8*)(q2 + (size_t)b * D_DIM);
  short8 qv0 = q2r[lane], qv1 = q2r[64 + lane];
  float q0[8], q1[8];
#pragma unroll
  for (int i = 0; i < 8; ++i) {
    q0[i] = bf2f((unsigned short)qv0[i]);
    q1[i] = bf2f((unsigned short)qv1[i]);
  }

  float s0[K_TOP], s1[K_TOP];
#pragma unroll
  for (int j = 0; j < K_TOP; ++j) {
    const short8* kr = (const short8*)(kb + (size_t)idx[j] * D_DIM);
    short8 k0 = kr[lane], k1 = kr[64 + lane];
    float p0 = 0.f, p1 = 0.f;
#pragma unroll
    for (int i = 0; i < 8; ++i) {
      p0 += q0[i] * bf2f((unsigned short)k0[i]);
      p1 += q1[i] * bf2f((unsigned short)k1[i]);
    }
    s0[j] = p0; s1[j] = p1;
  }
#pragma unroll
  for (int j = 0; j < K_TOP; ++j) {
#pragma unroll
    for (int o = 1; o < 8; o <<= 1) {
      s0[j] += __shfl_xor(s0[j], o);
      s1[j] += __shfl_xor(s1[j], o);
    }
  }

  float mx0 = -1e30f, mx1 = -1e30f;
#pragma unroll
  for (int j = 0; j < K_TOP; ++j) {
    mx0 = fmaxf(mx0, s0[j] * 0.125f);
    mx1 = fmaxf(mx1, s1[j] * 0.125f);
  }
  float w0[K_TOP], w1[K_TOP], sum0 = 0.f, sum1 = 0.f;
#pragma unroll
  for (int j = 0; j < K_TOP; ++j) {
    w0[j] = __expf(s0[j] * 0.125f - mx0); sum0 += w0[j];
    w1[j] = __expf(s1[j] * 0.125f - mx1); sum1 += w1[j];
  }
  const float inv0 = 1.0f / sum0, inv1 = 1.0f / sum1;
#pragma unroll
  for (int j = 0; j < K_TOP; ++j) { w0[j] *= inv0; w1[j] *= inv1; }

  float o0[8], o1[8];
#pragma unroll
  for (int i = 0; i < 8; ++i) { o0[i] = 0.f; o1[i] = 0.f; }
#pragma unroll
  for (int j = 0; j < K_TOP; ++j) {
    const short8* vr = (const short8*)(vb + (size_t)idx[j] * D_DIM);
    short8 v0 = vr[lane], v1 = vr[64 + lane];
#pragma unroll
    for (int i = 0; i < 8; ++i) {
      o0[i] += w0[j] * bf2f((unsigned short)v0[i]);
      o1[i] += w1[j] * bf2f((unsigned short)v1[i]);
    }
  }
  short8 c0, c1;
#pragma unroll
  for (int i = 0; i < 8; ++i) {
    c0[i] = (short)f2bf(o0[i]);
    c1[i] = (short)f2bf(o1[i]);
  }
  short8* cr = (short8*)(ctx + (size_t)b * D_DIM);
  cr[lane] = c0;
  cr[64 + lane] = c1;

  float t[K_TOP];
#pragma unroll
  for (int j = 0; j < K_TOP; ++j) t[j] = w0[j] + w1[j];
#pragma unroll
  for (int j = 0; j < K_TOP; ++j)
#pragma unroll
    for (int o = 32; o > 0; o >>= 1) t[j] += __shfl_xor(t[j], o);
  if (lane == 0) {
#pragma unroll
    for (int j = 0; j < K_TOP; ++j)
      attnw[(size_t)b * K_TOP + j] = t[j] * (1.0f / 128.0f);
  }
}

extern "C" void kernel_launch(void* const* d_in, const int* in_sizes, int n_in,
                              void* d_out, int out_size, void* d_ws, size_t ws_size,
                              hipStream_t stream) {
  const float* query   = (const float*)d_in[0];
  const float* bank    = (const float*)d_in[1];
  const float* logits  = (const float*)d_in[2];
  const float* Wq_proj = (const float*)d_in[3];
  const float* bq_proj = (const float*)d_in[4];
  const float* Wp_proj = (const float*)d_in[5];
  const float* bp_proj = (const float*)d_in[6];
  const float* Wq      = (const float*)d_in[7];
  const float* bq      = (const float*)d_in[8];
  const float* Wk      = (const float*)d_in[9];
  const float* bk      = (const float*)d_in[10];
  const float* Wv      = (const float*)d_in[11];
  const float* bv      = (const float*)d_in[12];
  const float* Wo      = (const float*)d_in[13];
  const float* bo      = (const float*)d_in[14];

  char* ws = (char*)d_ws;
  size_t off = 0;
  auto alloc = [&](size_t bytes) {
    void* p = ws + off;
    off += (bytes + 255) & ~(size_t)255;
    return p;
  };
  unsigned short* q_bf    = (unsigned short*)alloc((size_t)B_ROWS * D_DIM * 2); // query, then ctx
  unsigned short* bank_bf = (unsigned short*)alloc((size_t)P_ROWS * D_DIM * 2);
  unsigned short* q2_bf   = (unsigned short*)alloc((size_t)B_ROWS * D_DIM * 2);
  unsigned short* kb_bf   = (unsigned short*)alloc((size_t)P_ROWS * D_DIM * 2);
  unsigned short* vb_bf   = (unsigned short*)alloc((size_t)P_ROWS * D_DIM * 2);
  unsigned short* wq_bf   = (unsigned short*)alloc((size_t)D_DIM * D_DIM * 2);
  unsigned short* wk_bf   = (unsigned short*)alloc((size_t)D_DIM * D_DIM * 2);
  unsigned short* wv_bf   = (unsigned short*)alloc((size_t)D_DIM * D_DIM * 2);
  unsigned short* wo_bf   = (unsigned short*)alloc((size_t)D_DIM * D_DIM * 2);
  unsigned short* wqpT_bf = (unsigned short*)alloc((size_t)D_DIM * D_DIM * 2);
  unsigned short* wppT_bf = (unsigned short*)alloc((size_t)D_DIM * D_DIM * 2);
  unsigned short* wcq_bf  = (unsigned short*)alloc((size_t)D_DIM * D_DIM * 2);
  unsigned short* wck_bf  = (unsigned short*)alloc((size_t)D_DIM * D_DIM * 2);
  unsigned short* wcv_bf  = (unsigned short*)alloc((size_t)D_DIM * D_DIM * 2);
  float* bcq              = (float*)alloc(D_DIM * 4);
  float* bck              = (float*)alloc(D_DIM * 4);
  float* bcv              = (float*)alloc(D_DIM * 4);
  int* topk               = (int*)alloc((size_t)B_ROWS * K_TOP * 4);

  float* out_ctx  = (float*)d_out;
  float* out_attn = out_ctx + (size_t)B_ROWS * D_DIM;
  (void)out_ctx;

  // Phase A: top-k (butterfly merge) + converts + transposes + biases (R9 grid)
  PrepArgs pa;
  pa.cs[0] = query; pa.cd[0] = q_bf;
  pa.cs[1] = bank;  pa.cd[1] = bank_bf;
  pa.cs[2] = Wq;    pa.cd[2] = wq_bf;
  pa.cs[3] = Wk;    pa.cd[3] = wk_bf;
  pa.cs[4] = Wv;    pa.cd[4] = wv_bf;
  pa.cs[5] = Wo;    pa.cd[5] = wo_bf;
  pa.ts[0] = Wq_proj; pa.td[0] = wqpT_bf;
  pa.ts[1] = Wp_proj; pa.td[1] = wppT_bf;
  pa.bW[0] = Wq; pa.bp[0] = bq_proj; pa.bb[0] = bq; pa.bo[0] = bcq;
  pa.bW[1] = Wk; pa.bp[1] = bp_proj; pa.bb[1] = bk; pa.bo[1] = bck;
  pa.bW[2] = Wv; pa.bp[2] = bp_proj; pa.bb[2] = bv; pa.bo[2] = bcv;
  pa.logits = logits; pa.topk = topk;
  prep_kernel<<<PREP_BLOCKS, 256, 0, stream>>>(pa);

  // Phase B: weight-fusion GEMMs (small)
  MidArgs ma;
  ma.fA[0] = wq_bf; ma.fW[0] = wqpT_bf; ma.fC[0] = wcq_bf;
  ma.fA[1] = wk_bf; ma.fW[1] = wppT_bf; ma.fC[1] = wck_bf;
  ma.fA[2] = wv_bf; ma.fW[2] = wppT_bf; ma.fC[2] = wcv_bf;
  mid_kernel<<<MID_BLOCKS, 256, 0, stream>>>(ma);

  // Phase C: q2 + kb + vb GEMMs in one launch (XCD-chunked)
  Gemm3Args ga;
  ga.A[0] = q_bf;    ga.W[0] = wcq_bf; ga.bias[0] = bcq; ga.C[0] = q2_bf;
  ga.A[1] = bank_bf; ga.W[1] = wck_bf; ga.bias[1] = bck; ga.C[1] = kb_bf;
  ga.A[2] = bank_bf; ga.W[2] = wcv_bf; ga.bias[2] = bcv; ga.C[2] = vb_bf;
  gemm3_kernel<<<GEMM3_BLOCKS, 256, 0, stream>>>(ga);

  // Phase D: attention (ctx overwrites q_bf, which is free now); one wave per row
  attn_kernel<<<B_ROWS / 4, 256, 0, stream>>>(q2_bf, kb_bf, vb_bf, topk, q_bf, out_attn);

  // Phase E: context = ctx @ Wo^T + bo (fp32 out, XCD-chunked)
  gemm_o_kernel<<<512, 256, 0, stream>>>(q_bf, wo_bf, bo, (float*)d_out);
}